// Round 1
// baseline (279.215 us; speedup 1.0000x reference)
//
#include <hip/hip_runtime.h>

// LinearTimeMMDLoss: m=65536 rows, d=512, m2=32768 pairs.
// Pair p: x_odd=src[2p], x_even=src[2p+1], y_odd=tgt[2p], y_even=tgt[2p+1].
// h_p = sum_k [ e^{-dxx/b_k} + e^{-dyy/b_k} - e^{-dxy/b_k} - e^{-dyx/b_k} ],
// b_k = (dxx+dyy+dxy+dyx)/4 / 2^(5//2) * 2^k + 1e-6 ; out = mean_p h_p.
// Memory-bound: 256 MiB read once -> ~43 us floor at 6.3 TB/s.

#define D        512
#define M2       32768
#define NBLOCKS  2048
#define NTHREADS 256
#define WAVES_PB (NTHREADS / 64)

__global__ __launch_bounds__(NTHREADS) void mmd_pairs(const float* __restrict__ src,
                                                      const float* __restrict__ tgt,
                                                      float* __restrict__ partial) {
    const int lane = threadIdx.x & 63;
    const int wid  = threadIdx.x >> 6;
    const int stride = NBLOCKS * WAVES_PB;  // pairs per grid pass

    float acc = 0.0f;

    for (int pair = blockIdx.x * WAVES_PB + wid; pair < M2; pair += stride) {
        const float* xo = src + (size_t)2 * D * (size_t)pair;
        const float* xe = xo + D;
        const float* yo = tgt + (size_t)2 * D * (size_t)pair;
        const float* ye = yo + D;

        float sxx = 0.f, syy = 0.f, sxy = 0.f, syx = 0.f;

        // 64 lanes x (2 x float4) = 512 floats per row, fully coalesced.
#pragma unroll
        for (int c = 0; c < 2; ++c) {
            const int idx = c * 256 + lane * 4;
            const float4 a  = *reinterpret_cast<const float4*>(xo + idx);
            const float4 b  = *reinterpret_cast<const float4*>(xe + idx);
            const float4 g  = *reinterpret_cast<const float4*>(yo + idx);
            const float4 h4 = *reinterpret_cast<const float4*>(ye + idx);
#define COMP(f)                                   \
            { float t;                            \
              t = a.f - b.f;   sxx += t * t;      \
              t = g.f - h4.f;  syy += t * t;      \
              t = a.f - h4.f;  sxy += t * t;      \
              t = b.f - g.f;   syx += t * t; }
            COMP(x) COMP(y) COMP(z) COMP(w)
#undef COMP
        }

        // Wave-wide butterfly reduction (64 lanes) for the 4 distance sums.
#pragma unroll
        for (int off = 32; off > 0; off >>= 1) {
            sxx += __shfl_xor(sxx, off, 64);
            syy += __shfl_xor(syy, off, 64);
            sxy += __shfl_xor(sxy, off, 64);
            syx += __shfl_xor(syx, off, 64);
        }

        if (lane == 0) {
            // bw = (dxx+dyy+dxy+dyx)/4 / 2^(KERNEL_NUM//2) = sum/4/4
            const float bw = (sxx + syy + sxy + syx) * 0.25f * 0.25f;
            float h = 0.0f;
            float mult = 1.0f;
#pragma unroll
            for (int k = 0; k < 5; ++k) {
                const float bws = bw * mult + 1e-6f;
                h += expf(-sxx / bws) + expf(-syy / bws)
                   - expf(-sxy / bws) - expf(-syx / bws);
                mult *= 2.0f;  // KERNEL_MUL = 2
            }
            acc += h;
        }
    }

    // Only lane 0 of each wave holds a nonzero acc.
    __shared__ float red[WAVES_PB];
    if (lane == 0) red[wid] = acc;
    __syncthreads();
    if (threadIdx.x == 0) {
        float s = 0.f;
#pragma unroll
        for (int i = 0; i < WAVES_PB; ++i) s += red[i];
        partial[blockIdx.x] = s;
    }
}

__global__ __launch_bounds__(256) void mmd_final(const float* __restrict__ partial,
                                                 float* __restrict__ out) {
    float s = 0.f;
    for (int i = threadIdx.x; i < NBLOCKS; i += 256) s += partial[i];
#pragma unroll
    for (int off = 32; off > 0; off >>= 1) s += __shfl_xor(s, off, 64);
    __shared__ float red[4];
    if ((threadIdx.x & 63) == 0) red[threadIdx.x >> 6] = s;
    __syncthreads();
    if (threadIdx.x == 0)
        out[0] = (red[0] + red[1] + red[2] + red[3]) * (1.0f / (float)M2);
}

extern "C" void kernel_launch(void* const* d_in, const int* in_sizes, int n_in,
                              void* d_out, int out_size, void* d_ws, size_t ws_size,
                              hipStream_t stream) {
    const float* src = (const float*)d_in[0];
    const float* tgt = (const float*)d_in[1];
    float* out = (float*)d_out;
    float* partial = (float*)d_ws;  // NBLOCKS floats = 8 KiB; fully written before read

    mmd_pairs<<<NBLOCKS, NTHREADS, 0, stream>>>(src, tgt, partial);
    mmd_final<<<1, 256, 0, stream>>>(partial, out);
}

// Round 2
// 272.160 us; speedup vs baseline: 1.0259x; 1.0259x over previous
//
#include <hip/hip_runtime.h>

// LinearTimeMMDLoss: m=65536, d=512, m2=32768 pairs.
// One wave per pair; 20 exp terms distributed across lanes (r=lane&3 picks the
// distance, k=lane>>2 picks the bandwidth); per-lane acc summed once at the end.
// Memory-bound target: 256 MiB touched once (~half served by L3 after the
// harness restore-copy) -> ~35-45 us floor.

#define D        512
#define M2       32768
#define NBLOCKS  2048
#define NTHREADS 256
#define WPB      (NTHREADS / 64)      // 4 waves per block
#define NWAVES   (NBLOCKS * WPB)      // 8192
#define PPW      (M2 / NWAVES)        // 4 pairs per wave, exact cover

__global__ __launch_bounds__(NTHREADS) void mmd_pairs(const float* __restrict__ src,
                                                      const float* __restrict__ tgt,
                                                      float* __restrict__ out) {
    const int lane = threadIdx.x & 63;
    const int wid  = threadIdx.x >> 6;
    const int wave = blockIdx.x * WPB + wid;

    // Per-lane constant term assignment: lanes 0..19 own one of the 20 terms.
    const int   r    = lane & 3;             // 0:dxx 1:dyy 2:dxy 3:dyx
    const int   k    = lane >> 2;            // bandwidth index (valid k<5)
    const float mult = (float)(1 << k);      // 2^k
    const float sgn  = (k < 5) ? ((r < 2) ? 1.0f : -1.0f) : 0.0f;

    float acc = 0.0f;

#pragma unroll 2
    for (int i = 0; i < PPW; ++i) {
        const int pair = wave + i * NWAVES;
        const float* xo = src + (size_t)(2 * D) * (size_t)pair;
        const float* xe = xo + D;
        const float* yo = tgt + (size_t)(2 * D) * (size_t)pair;
        const float* ye = yo + D;

        float sxx = 0.f, syy = 0.f, sxy = 0.f, syx = 0.f;

        // 64 lanes x (2 x float4) = 512 floats per row, fully coalesced.
#pragma unroll
        for (int c = 0; c < 2; ++c) {
            const int idx = c * 256 + lane * 4;
            const float4 a  = *reinterpret_cast<const float4*>(xo + idx);
            const float4 b  = *reinterpret_cast<const float4*>(xe + idx);
            const float4 g  = *reinterpret_cast<const float4*>(yo + idx);
            const float4 h4 = *reinterpret_cast<const float4*>(ye + idx);
#define COMP(f)                                   \
            { float t;                            \
              t = a.f - b.f;   sxx += t * t;      \
              t = g.f - h4.f;  syy += t * t;      \
              t = a.f - h4.f;  sxy += t * t;      \
              t = b.f - g.f;   syx += t * t; }
            COMP(x) COMP(y) COMP(z) COMP(w)
#undef COMP
        }

        // Wave-wide butterfly: all lanes end up with the four full sums.
#pragma unroll
        for (int off = 32; off > 0; off >>= 1) {
            sxx += __shfl_xor(sxx, off, 64);
            syy += __shfl_xor(syy, off, 64);
            sxy += __shfl_xor(sxy, off, 64);
            syx += __shfl_xor(syx, off, 64);
        }

        // bw = (sum of 4 distances)/4 / 2^(5//2) = sum/16
        const float bw   = (sxx + syy + sxy + syx) * 0.0625f;
        const float bws  = bw * mult + 1e-6f;
        const float dsel = (r & 2) ? ((r & 1) ? syx : sxy)
                                   : ((r & 1) ? syy : sxx);
        acc += sgn * expf(-dsel / bws);   // sgn==0 masks lanes 20..63
    }

    // End-of-block reduction: wave butterfly -> LDS -> one atomic per block.
#pragma unroll
    for (int off = 32; off > 0; off >>= 1) acc += __shfl_xor(acc, off, 64);

    __shared__ float red[WPB];
    if (lane == 0) red[wid] = acc;
    __syncthreads();
    if (threadIdx.x == 0) {
        float s = 0.f;
#pragma unroll
        for (int i = 0; i < WPB; ++i) s += red[i];
        atomicAdd(out, s * (1.0f / (float)M2));
    }
}

extern "C" void kernel_launch(void* const* d_in, const int* in_sizes, int n_in,
                              void* d_out, int out_size, void* d_ws, size_t ws_size,
                              hipStream_t stream) {
    const float* src = (const float*)d_in[0];
    const float* tgt = (const float*)d_in[1];
    float* out = (float*)d_out;

    hipMemsetAsync(out, 0, sizeof(float), stream);  // d_out is poisoned 0xAA
    mmd_pairs<<<NBLOCKS, NTHREADS, 0, stream>>>(src, tgt, out);
}